// Round 5
// baseline (77.013 us; speedup 1.0000x reference)
//
#include <hip/hip_runtime.h>

#define B_ 4
#define N_ 2048
#define IND_ 128
#define H_ 4
#define D_ 64
#define HD_ 256
#define LEAKY 0.2f
#define BNEPS 1e-5f
#define LOG2E 1.44269504088896340736f

typedef float f32x4 __attribute__((ext_vector_type(4)));
typedef short s16x8 __attribute__((ext_vector_type(8)));
typedef unsigned int u32x4 __attribute__((ext_vector_type(4)));

static __device__ __forceinline__ unsigned short f2bf(float f) {
  unsigned u = __builtin_bit_cast(unsigned, f);
  u = (u + 0x7fffu + ((u >> 16) & 1u)) >> 16;   // RNE
  return (unsigned short)u;
}
static __device__ __forceinline__ unsigned encf(float f) {
  unsigned u = __builtin_bit_cast(unsigned, f);
  return (u & 0x80000000u) ? ~u : (u | 0x80000000u);
}
static __device__ __forceinline__ float decf(unsigned u) {
  unsigned b = (u & 0x80000000u) ? (u ^ 0x80000000u) : ~u;
  return __builtin_bit_cast(float, b);
}

// ---------------- Kernel A: pack adjacency + zero accumulators ------------
__global__ __launch_bounds__(256) void k_pack_adj(const int* __restrict__ adj,
                                                  unsigned* __restrict__ bits,
                                                  float* __restrict__ zbuf) {
  // zero chsum(256) | chsq(256) | dmaxU(64) = 576 floats
  if (blockIdx.x == 0) {
    for (int i = threadIdx.x; i < 576; i += 256) zbuf[i] = 0.f;
  }
  int idx = blockIdx.x * 256 + threadIdx.x;     // flat over N*N (row-major)
  int val = adj[idx] != 0;
  unsigned long long m = __ballot(val);
  int lane = threadIdx.x & 63;
  if (lane == 0)       bits[idx >> 5] = (unsigned)m;
  else if (lane == 32) bits[idx >> 5] = (unsigned)(m >> 32);
}

// ---------------- Kernel B: Wh = h @ W (bf16, transposed) + src/dst -------
// 512 blocks x 16 rows. wht layout: [bh][d][n] bf16. Emits srcL/dstL
// (pre-scaled by log2e) and per-bh dstL max (order-preserving atomicMax).
__global__ __launch_bounds__(256) void k_gemm(const float* __restrict__ h,
                                              const float* __restrict__ W,
                                              const float* __restrict__ a,
                                              unsigned short* __restrict__ wht,
                                              float* __restrict__ src,
                                              float* __restrict__ dst,
                                              unsigned* __restrict__ dmaxU) {
  __shared__ float hl[16 * 128];     // 8 KB
  __shared__ float tr[256 * 17];     // 17 KB transpose buffer
  int t = threadIdx.x;
  int rowbase = blockIdx.x * 16;               // global row m in [0, B*N)
  const f32x4* hg = (const f32x4*)(h + (size_t)rowbase * 128);
  f32x4* hl4 = (f32x4*)hl;
  hl4[t] = hg[t];
  hl4[t + 256] = hg[t + 256];
  __syncthreads();

  int lane = t & 63, q = t >> 6;               // wave q owns rows q*4..q*4+3
  float acc[4][4];
#pragma unroll
  for (int rr = 0; rr < 4; rr++)
#pragma unroll
    for (int cc = 0; cc < 4; cc++) acc[rr][cc] = 0.f;

#pragma unroll 2
  for (int k4 = 0; k4 < 32; k4++) {
    f32x4 hv[4], wv[4];
#pragma unroll
    for (int rr = 0; rr < 4; rr++)
      hv[rr] = *(const f32x4*)&hl[(q * 4 + rr) * 128 + k4 * 4];
#pragma unroll
    for (int kk = 0; kk < 4; kk++)
      wv[kk] = *(const f32x4*)(W + (size_t)(k4 * 4 + kk) * 256 + lane * 4);
#pragma unroll
    for (int kk = 0; kk < 4; kk++)
#pragma unroll
      for (int rr = 0; rr < 4; rr++)
#pragma unroll
        for (int cc = 0; cc < 4; cc++)
          acc[rr][cc] = fmaf(hv[rr][kk], wv[kk][cc], acc[rr][cc]);
  }

  // ---- fused src/dst: thread's 4 channels (lane*4..) share hh = lane>>4
  int b = rowbase >> 11, n0 = rowbase & 2047;
  {
    int hh = lane >> 4;
    int dbase = (lane & 15) * 4;
    float aS[4], aD[4];
#pragma unroll
    for (int cc = 0; cc < 4; cc++) {
      aS[cc] = a[hh * 128 + dbase + cc] * LOG2E;
      aD[cc] = a[hh * 128 + 64 + dbase + cc] * LOG2E;
    }
    float dmx = -1e30f;
#pragma unroll
    for (int rr = 0; rr < 4; rr++) {
      float sv = 0.f, dv = 0.f;
#pragma unroll
      for (int cc = 0; cc < 4; cc++) {
        sv = fmaf(acc[rr][cc], aS[cc], sv);
        dv = fmaf(acc[rr][cc], aD[cc], dv);
      }
#pragma unroll
      for (int off = 1; off < 16; off <<= 1) {
        sv += __shfl_xor(sv, off);
        dv += __shfl_xor(dv, off);
      }
      if ((lane & 15) == 0) {
        int n = n0 + q * 4 + rr;
        src[(size_t)(b * 4 + hh) * 2048 + n] = sv;
        dst[(size_t)(b * 4 + hh) * 2048 + n] = dv;
        dmx = fmaxf(dmx, dv);
      }
    }
    if ((lane & 15) == 0) atomicMax(&dmaxU[b * 4 + hh], encf(dmx));
  }

  // ---- transpose through LDS (pad 17), emit bf16 wht
#pragma unroll
  for (int rr = 0; rr < 4; rr++)
#pragma unroll
    for (int cc = 0; cc < 4; cc++)
      tr[(lane * 4 + cc) * 17 + q * 4 + rr] = acc[rr][cc];
  __syncthreads();

  int c = t;                 // output channel 0..255
  int d = c & 63, hh = c >> 6;
  u32x4 wv2[2];
#pragma unroll
  for (int i = 0; i < 2; i++) {
#pragma unroll
    for (int jj = 0; jj < 4; jj++) {
      unsigned lo = f2bf(tr[c * 17 + (i * 4 + jj) * 2]);
      unsigned hi = f2bf(tr[c * 17 + (i * 4 + jj) * 2 + 1]);
      wv2[i][jj] = lo | (hi << 16);
    }
  }
  u32x4* outp = (u32x4*)(wht + ((size_t)((b * H_ + hh) * 64 + d)) * 2048 + n0);
  outp[0] = wv2[0];
  outp[1] = wv2[1];
}

// ---------------- Kernel C: flash attention, factorized scores ------------
// p = max(A_i*u_j, B_i*v_j): no transcendental in the inner loop.
// Denominator via 5th MFMA (af x ones) -> lands per-row in accd[r].
// 512 threads: waves 0-3 j in [0,1024), waves 4-7 j in [1024,2048).
__global__ __launch_bounds__(512) void k_attn(const unsigned* __restrict__ adjb,
                                              const unsigned short* __restrict__ wht,
                                              const float* __restrict__ src,
                                              const float* __restrict__ dst,
                                              const unsigned* __restrict__ dmaxU,
                                              float* __restrict__ hnew,
                                              float* __restrict__ chsum,
                                              float* __restrict__ chsq) {
  __shared__ unsigned adj_lds[64 * 65];   // 16.6KB; reused as f32 acc-combine buf
  __shared__ u32x4 whb4[2048];            // 2 halves x 2 dbuf x 8KB, XOR-swizzled
  __shared__ float ul[2048], vl[2048];    // 16KB: u_j = 2^dstL, v_j = 2^(.2 dstL)
  __shared__ float redS[256], redQ[256];

  int t = threadIdx.x;
  int bid = blockIdx.x;
  int bh = bid & 15, it = bid >> 4;       // 16 consecutive blocks share adj rows (L2)
  int b = bh >> 2, hh = bh & 3;
  int i0 = it * 64;
  int w8 = t >> 6, half = w8 >> 2, w = w8 & 3;
  int lane = t & 63, m = lane & 15, g = lane >> 4;

  for (int idx = t; idx < 64 * 64; idx += 512) {
    int r = idx >> 6, wd = idx & 63;
    adj_lds[r * 65 + wd] = adjb[(size_t)(i0 + r) * 64 + wd];
  }
  {
    f32x4 dv = ((const f32x4*)(dst + (size_t)bh * 2048))[t];
    f32x4 uu, vv;
#pragma unroll
    for (int e = 0; e < 4; e++) {
      uu[e] = __builtin_amdgcn_exp2f(dv[e]);
      vv[e] = __builtin_amdgcn_exp2f(0.2f * dv[e]);
    }
    ((f32x4*)ul)[t] = uu;
    ((f32x4*)vl)[t] = vv;
  }

  int row_i = i0 + w * 16 + m;            // A-operand row this lane fills
  float srcL = src[(size_t)bh * 2048 + row_i];
  float dmaxL = decf(dmaxU[bh]);
  float sML = srcL + dmaxL;
  float negM = -fmaxf(sML, LEAKY * sML);  // -(row score upper bound), log2 domain
  float Af = __builtin_amdgcn_exp2f(srcL + negM);
  float Bf = __builtin_amdgcn_exp2f(fmaf(LEAKY, srcL, negM));

  s16x8 bones;
#pragma unroll
  for (int e = 0; e < 8; e++) bones[e] = (short)0x3F80;   // bf16 1.0

  f32x4 acc[4], accd;
#pragma unroll
  for (int db = 0; db < 4; db++) acc[db] = (f32x4){0.f, 0.f, 0.f, 0.f};
  accd = (f32x4){0.f, 0.f, 0.f, 0.f};

  char* wbase = (char*)whb4 + half * 16384;
  int ts = t & 255;
  int r_ = ts >> 2, ch_ = ts & 3;
  int jtbase = half * 16;
  const char* gbase = (const char*)(wht + (size_t)(bh * 64 + r_) * 2048) + jtbase * 128;
  int sw = (r_ & 7) << 4;
  u32x4 R0, R1;

#define LOADT(jt_) { const u32x4* gp = (const u32x4*)(gbase + (jt_) * 128 + ch_ * 32); \
                     R0 = gp[0]; R1 = gp[1]; }
#define WRITET(pb_) { char* wb_ = (pb_); \
                      *(u32x4*)(wb_ + r_ * 128 + ((ch_ * 32) ^ sw)) = R0; \
                      *(u32x4*)(wb_ + r_ * 128 + ((ch_ * 32 + 16) ^ sw)) = R1; }

  LOADT(0); WRITET(wbase); LOADT(1);

  for (int jt = 0; jt < 16; jt++) {
    int cur = jt & 1;
    __syncthreads();                      // drains prefetch vmem + dbuf writes
    if (jt < 15) WRITET(wbase + (cur ^ 1) * 8192);   // tile jt+1 -> other buf
    if (jt < 14) LOADT(jt + 2);                      // issue tile jt+2 loads
    const char* wbufc = wbase + cur * 8192;
    int jglob = jtbase + jt;

#pragma unroll
    for (int ks = 0; ks < 2; ks++) {
      unsigned adjw = adj_lds[(w * 16 + m) * 65 + jglob * 2 + ks];
      unsigned bits = (adjw >> (g * 8)) & 0xffu;
      const float* up = &ul[jglob * 64 + ks * 32 + g * 8];
      const float* vp = &vl[jglob * 64 + ks * 32 + g * 8];
      f32x4 u0 = *(const f32x4*)up, u1 = *(const f32x4*)(up + 4);
      f32x4 v0 = *(const f32x4*)vp, v1 = *(const f32x4*)(vp + 4);
      float pm[8];
#pragma unroll
      for (int e = 0; e < 8; e++) {
        float ue = (e < 4) ? u0[e] : u1[e - 4];
        float ve = (e < 4) ? v0[e] : v1[e - 4];
        float p = fmaxf(Af * ue, Bf * ve);            // leaky-exp, factorized
        unsigned keep = (unsigned)(((int)(bits << (31 - e))) >> 31);
        pm[e] = __builtin_bit_cast(float, __builtin_bit_cast(unsigned, p) & keep);
      }
      u32x4 afu;
#pragma unroll
      for (int e2 = 0; e2 < 4; e2++) {
        unsigned rr_;
        asm("v_cvt_pk_bf16_f32 %0, %1, %2" : "=v"(rr_) : "v"(pm[2 * e2]), "v"(pm[2 * e2 + 1]));
        afu[e2] = rr_;
      }
      s16x8 af = __builtin_bit_cast(s16x8, afu);
#pragma unroll
      for (int db = 0; db < 4; db++) {
        int dl = db * 16 + m;
        int off = dl * 128 + ((ks * 64 + g * 16) ^ ((dl & 7) << 4));
        s16x8 bf = *(const s16x8*)(wbufc + off);
        acc[db] = __builtin_amdgcn_mfma_f32_16x16x32_bf16(af, bf, acc[db], 0, 0, 0);
      }
      accd = __builtin_amdgcn_mfma_f32_16x16x32_bf16(af, bones, accd, 0, 0, 0);
    }
  }
#undef LOADT
#undef WRITET

  __syncthreads();                        // both halves done with adj_lds reads
  float* accl = (float*)adj_lds;          // reuse: [row][65] (col 64 = den)
  if (half == 1) {
#pragma unroll
    for (int db = 0; db < 4; db++)
#pragma unroll
      for (int r = 0; r < 4; r++)
        accl[(w * 16 + 4 * g + r) * 65 + db * 16 + m] = acc[db][r];
    if (m == 0) {
#pragma unroll
      for (int r = 0; r < 4; r++)
        accl[(w * 16 + 4 * g + r) * 65 + 64] = accd[r];
    }
  }
  __syncthreads();

  if (half == 0) {
#pragma unroll
    for (int db = 0; db < 4; db++)
#pragma unroll
      for (int r = 0; r < 4; r++)
        acc[db][r] += accl[(w * 16 + 4 * g + r) * 65 + db * 16 + m];
    float inv[4];
#pragma unroll
    for (int r = 0; r < 4; r++) {
      float dtot = accd[r] + accl[(w * 16 + 4 * g + r) * 65 + 64];
      inv[r] = dtot > 0.f ? 1.0f / dtot : 0.f;  // all-masked row -> zeros
    }

    float sums[4] = {0.f, 0.f, 0.f, 0.f}, sqs[4] = {0.f, 0.f, 0.f, 0.f};
#pragma unroll
    for (int r = 0; r < 4; r++) {
      int n = i0 + w * 16 + 4 * g + r;
#pragma unroll
      for (int db = 0; db < 4; db++) {
        float val = acc[db][r] * inv[r];
        hnew[(size_t)(b * 2048 + n) * 256 + hh * 64 + db * 16 + m] = val;
        sums[db] += val;
        sqs[db] += val * val;
      }
    }
#pragma unroll
    for (int db = 0; db < 4; db++) {
      sums[db] += __shfl_xor(sums[db], 16); sums[db] += __shfl_xor(sums[db], 32);
      sqs[db]  += __shfl_xor(sqs[db], 16);  sqs[db]  += __shfl_xor(sqs[db], 32);
    }
    if (g == 0) {
#pragma unroll
      for (int db = 0; db < 4; db++) {
        redS[w * 64 + db * 16 + m] = sums[db];
        redQ[w * 64 + db * 16 + m] = sqs[db];
      }
    }
  }
  __syncthreads();
  if (t < 64) {
    float ts2 = redS[t] + redS[64 + t] + redS[128 + t] + redS[192 + t];
    float tq = redQ[t] + redQ[64 + t] + redQ[128 + t] + redQ[192 + t];
    atomicAdd(&chsum[hh * 64 + t], ts2);
    atomicAdd(&chsq[hh * 64 + t], tq);
  }
}

// ---------------- Kernel D: BN(+stats inline) + ELU -----------------------
__global__ __launch_bounds__(256) void k_bn_elu(const float* __restrict__ hnew,
                                                const float* __restrict__ chsum,
                                                const float* __restrict__ chsq,
                                                const float* __restrict__ gamma,
                                                const float* __restrict__ beta,
                                                float* __restrict__ out) {
  int idx4 = blockIdx.x * 256 + threadIdx.x;
  f32x4 x = ((const f32x4*)hnew)[idx4];
  int c0 = (idx4 * 4) & 255;
  f32x4 s = *(const f32x4*)(chsum + c0);
  f32x4 sq = *(const f32x4*)(chsq + c0);
  f32x4 gm = *(const f32x4*)(gamma + c0);
  f32x4 bt = *(const f32x4*)(beta + c0);
  f32x4 y;
#pragma unroll
  for (int e = 0; e < 4; e++) {
    float mean = s[e] * (1.0f / 8192.0f);
    float var = sq[e] * (1.0f / 8192.0f) - mean * mean;
    float sc = gm[e] * rsqrtf(var + BNEPS);
    float v = (x[e] - mean) * sc + bt[e];
    y[e] = v > 0.f ? v : expm1f(v);
  }
  ((f32x4*)out)[idx4] = y;
}

extern "C" void kernel_launch(void* const* d_in, const int* in_sizes, int n_in,
                              void* d_out, int out_size, void* d_ws, size_t ws_size,
                              hipStream_t stream) {
  const float* h = (const float*)d_in[0];
  const float* W = (const float*)d_in[1];
  const float* a = (const float*)d_in[2];
  const float* gamma = (const float*)d_in[3];
  const float* beta = (const float*)d_in[4];
  const int* adj = (const int*)d_in[5];

  char* ws = (char*)d_ws;
  unsigned* adjb = (unsigned*)ws;                                  // 512 KB
  unsigned short* wht = (unsigned short*)(ws + (512 << 10));       // 4 MB
  float* src = (float*)(ws + (512 << 10) + (4 << 20));             // 128 KB
  float* dst = src + 16 * 2048;                                    // 128 KB
  float* chsum = dst + 16 * 2048;                                  // 256
  float* chsq = chsum + 256;                                       // 256
  unsigned* dmaxU = (unsigned*)(chsq + 256);                       // 64
  float* hnew = (float*)(ws + (512 << 10) + (5 << 20));            // 8 MB

  k_pack_adj<<<(N_ * N_) / 256, 256, 0, stream>>>(adj, adjb, chsum);
  k_gemm<<<(B_ * N_) / 16, 256, 0, stream>>>(h, W, a, wht, src, dst, dmaxU);
  k_attn<<<B_ * H_ * (N_ / 64), 512, 0, stream>>>(adjb, wht, src, dst, dmaxU,
                                                  hnew, chsum, chsq);
  k_bn_elu<<<(B_ * N_ * HD_) / 1024, 256, 0, stream>>>(hnew, chsum, chsq,
                                                       gamma, beta, (float*)d_out);
}